// Round 1
// baseline (252.775 us; speedup 1.0000x reference)
//
#include <hip/hip_runtime.h>
#include <hip/hip_bf16.h>
#include <stdint.h>

typedef __bf16 bf16x8 __attribute__((ext_vector_type(8)));
typedef float floatx4 __attribute__((ext_vector_type(4)));

// ---------------------------------------------------------------------------
// Async global->LDS 16B copy (wave-uniform LDS base + lane*16; per-lane
// global address OK).
// ---------------------------------------------------------------------------
__device__ __forceinline__ void async_copy16(void* lds, const void* g) {
    __builtin_amdgcn_global_load_lds(
        (const __attribute__((address_space(1))) unsigned int*)g,
        (__attribute__((address_space(3))) unsigned int*)lds,
        16, 0, 0);
}

// ---------------------------------------------------------------------------
// Fused prep, one dispatch (UNCHANGED from r6 — isolate the gemm change):
//   blocks [0, nConv)         : x fp32 -> bf16 (8 elems/thread, float4 loads)
//   blocks [nConv, nConv+1280): Wrot[o,d] = sum_k kron(K1,K2,K3)[d,k] W[o,k]
// ---------------------------------------------------------------------------
__global__ __launch_bounds__(256)
void prep(const float* __restrict__ x,
          const float* __restrict__ W,
          const float* __restrict__ K1,
          const float* __restrict__ K2,
          const float* __restrict__ K3,
          __hip_bfloat16* __restrict__ x_bf,
          __hip_bfloat16* __restrict__ Wrot,
          int nConv) {
    const int tid = threadIdx.x;

    if ((int)blockIdx.x < nConv) {
        const size_t i = ((size_t)blockIdx.x * 256 + tid) * 8;
        const float4 a = *(const float4*)(x + i);
        const float4 b = *(const float4*)(x + i + 4);
        bf16x8 v;
        v[0] = (__bf16)a.x; v[1] = (__bf16)a.y; v[2] = (__bf16)a.z; v[3] = (__bf16)a.w;
        v[4] = (__bf16)b.x; v[5] = (__bf16)b.y; v[6] = (__bf16)b.z; v[7] = (__bf16)b.w;
        *(bf16x8*)((__bf16*)x_bf + i) = v;
        return;
    }

    const int o = blockIdx.x - nConv;
    __shared__ __align__(16) float w0[1280];   // W row, then stage-2 result
    __shared__ __align__(16) float t1[1280];
    __shared__ __align__(16) float k3s[1600];
    __shared__ float k2s[64];
    __shared__ float k1s[16];

    for (int i = tid; i < 1280; i += 256) w0[i] = W[o * 1280 + i];
    for (int i = tid; i < 1600; i += 256) k3s[i] = K3[i];
    if (tid < 64) k2s[tid] = K2[tid];
    if (tid < 16) k1s[tid] = K1[tid];
    __syncthreads();

    // stage 1: t1[p*40 + d3] = sum_k3 w0[p*40+k3] * K3[d3,k3]  (float4 LDS)
    for (int i = tid; i < 1280; i += 256) {
        const int p = i / 40, d3 = i % 40;
        const float4* w4 = (const float4*)(w0 + p * 40);
        const float4* k4 = (const float4*)(k3s + d3 * 40);
        float acc = 0.f;
#pragma unroll
        for (int t = 0; t < 10; ++t) {
            const float4 a = w4[t], b = k4[t];
            acc += a.x * b.x + a.y * b.y + a.z * b.z + a.w * b.w;
        }
        t1[i] = acc;
    }
    __syncthreads();

    // stage 2: w0[(k1*8+d2)*40+d3] = sum_k2 t1[(k1*8+k2)*40+d3] * K2[d2,k2]
    for (int i = tid; i < 1280; i += 256) {
        const int d3 = i % 40, pd = i / 40;
        const int k1 = pd >> 3, d2 = pd & 7;
        float acc = 0.f;
#pragma unroll
        for (int k2 = 0; k2 < 8; ++k2) acc += t1[(k1 * 8 + k2) * 40 + d3] * k2s[d2 * 8 + k2];
        w0[i] = acc;
    }
    __syncthreads();

    // stage 3: Wrot[o,(d1*8+d2)*40+d3] = sum_k1 w0[(k1*8+d2)*40+d3] * K1[d1,k1]
    for (int i = tid; i < 1280; i += 256) {
        const int d3 = i % 40, pd = i / 40;
        const int d1 = pd >> 3, d2 = pd & 7;
        float acc = 0.f;
#pragma unroll
        for (int k1 = 0; k1 < 4; ++k1) acc += w0[(k1 * 8 + d2) * 40 + d3] * k1s[d1 * 4 + k1];
        Wrot[(size_t)o * 1280 + i] = __float2bfloat16(acc);
    }
}

// ---------------------------------------------------------------------------
// Main GEMM r7: C[m,n] = sum_k A[m,k] * B[n,k]   (bf16 in, fp32 out/acc)
//
// NEW vs r6: T3+T4 counted-vmcnt pipeline (deep prefetch across barriers).
//   - 256x128 tile, 512 threads = 8 waves (4M x 2N), 64x64/wave via 4x4
//     mfma_f32_16x16x32_bf16, BK=64.
//   - TRIPLE-buffered LDS (144 KiB): tile t in buf[t%3]; at iter t we issue
//     tile t+2's 6 global_load_lds into the buffer tile t-1 vacated (safe:
//     all waves passed iter t-1's end barrier), then s_waitcnt vmcnt(12)
//     (waits tile t's 6 loads only; t+1/t+2's 12 stay IN FLIGHT across the
//     barrier), raw s_barrier, compute, s_barrier. Loads get ~2 iterations
//     (~2500 cyc) to cover the ~900-cyc HBM latency instead of the r6
//     __syncthreads() vmcnt(0) drain every K-step.
//   - Tail: vmcnt(6) at t=nk-2, vmcnt(0) at t=nk-1.
//   - T5: s_setprio(1) around each 16-MFMA cluster.
//   - Keeps r4's XOR k-granule swizzle folded into GLOBAL addresses
//     (0 bank conflicts measured) and r6's XCD chunking (640 blocks,
//     640 % 8 == 0, bijective; 8 M-tiles x 10 N-tiles per XCD).
//   - Per-output accumulation order identical to r6 -> same numerics.
// ---------------------------------------------------------------------------
#define BM 256
#define BN 128
#define BK 64
#define AG (BM * BK / 8)   // 2048 granules (bf16x8) per A buffer = 32 KiB
#define BG (BN * BK / 8)   // 1024 granules per B buffer = 16 KiB

__device__ __forceinline__ void stage_tile(const __hip_bfloat16* __restrict__ A,
                                           const __hip_bfloat16* __restrict__ B,
                                           bf16x8* Asb, bf16x8* Bsb,
                                           int tileM, int tileN, int K, int kt,
                                           int wave, int lane) {
    // A: 2048 granules / 512 threads = 4 chunks; B: 1024 / 512 = 2 chunks.
    // granule g holds row m = g>>3, phys slot p = g&7, data k-granule p^(m&7).
#pragma unroll
    for (int c = 0; c < 4; ++c) {
        const int g  = c * 512 + wave * 64 + lane;
        const int m  = g >> 3;
        const int kv = (g & 7) ^ (m & 7);
        async_copy16(&Asb[c * 512 + wave * 64],
                     A + (size_t)(tileM + m) * K + kt + kv * 8);
    }
#pragma unroll
    for (int c = 0; c < 2; ++c) {
        const int g  = c * 512 + wave * 64 + lane;
        const int m  = g >> 3;
        const int kv = (g & 7) ^ (m & 7);
        async_copy16(&Bsb[c * 512 + wave * 64],
                     B + (size_t)(tileN + m) * K + kt + kv * 8);
    }
}

__global__ __launch_bounds__(512, 2)
void gemm_bt(const __hip_bfloat16* __restrict__ A,   // [M,K] bf16
             const __hip_bfloat16* __restrict__ B,   // [N,K] bf16
             float* __restrict__ C,                  // [M,N] fp32
             int M, int N, int K) {
    __shared__ bf16x8 As[3 * AG];   // 96 KiB
    __shared__ bf16x8 Bs[3 * BG];   // 48 KiB

    const int tid  = threadIdx.x;
    const int wave = tid >> 6;
    const int lane = tid & 63;
    const int q    = lane >> 4;
    const int r16  = lane & 15;

    // XCD-partitioned tile assignment (grid = 64 * 10 = 640, 8 | 640)
    const int nTilesN = N / BN;               // 10
    const int nTilesM = M / BM;               // 64
    const int chunk   = nTilesM >> 3;         // 8 M-tiles per XCD
    const int xcd = blockIdx.x & 7;
    const int s   = blockIdx.x >> 3;          // 0..79 within XCD
    const int bm  = xcd * chunk + s / nTilesN;
    const int bn  = s % nTilesN;
    const int tileM = bm * BM, tileN = bn * BN;
    const int wm = wave >> 1, wn = wave & 1;  // 4M x 2N wave grid

    floatx4 acc[4][4];
#pragma unroll
    for (int i = 0; i < 4; ++i)
#pragma unroll
        for (int j = 0; j < 4; ++j) acc[i][j] = (floatx4){0.f, 0.f, 0.f, 0.f};

    const int nk = K / BK;                    // 20

    // Prologue: tiles 0 and 1 in flight (6 loads/thread each).
    stage_tile(A, B, &As[0], &Bs[0], tileM, tileN, K, 0, wave, lane);
    if (nk > 1)
        stage_tile(A, B, &As[AG], &Bs[BG], tileM, tileN, K, BK, wave, lane);

    int cur = 0;                              // buffer of tile t
    for (int t = 0; t < nk; ++t) {
        if (t + 2 < nk) {
            // tile t+2 -> buffer (cur+2)%3, vacated by tile t-1 at the
            // previous end-of-iter barrier.
            const int nx = (cur >= 1) ? cur - 1 : cur + 2;
            stage_tile(A, B, &As[nx * AG], &Bs[nx * BG],
                       tileM, tileN, K, (t + 2) * BK, wave, lane);
            asm volatile("s_waitcnt vmcnt(12)" ::: "memory");  // t landed; t+1,t+2 in flight
        } else if (t + 1 < nk) {
            asm volatile("s_waitcnt vmcnt(6)" ::: "memory");   // t landed; t+1 in flight
        } else {
            asm volatile("s_waitcnt vmcnt(0)" ::: "memory");   // drain (last tile)
        }
        __builtin_amdgcn_s_barrier();          // all waves' tile-t data visible
        asm volatile("" ::: "memory");         // fence: no ds_read hoists above

        const bf16x8* Ab = &As[cur * AG];
        const bf16x8* Bb = &Bs[cur * BG];
#pragma unroll
        for (int s2 = 0; s2 < 2; ++s2) {
            bf16x8 af[4], bfr[4];
            const int kv = s2 * 4 + q;
#pragma unroll
            for (int i = 0; i < 4; ++i) {
                const int m = wm * 64 + i * 16 + r16;
                af[i] = Ab[m * 8 + (kv ^ (m & 7))];
                const int n = wn * 64 + i * 16 + r16;
                bfr[i] = Bb[n * 8 + (kv ^ (n & 7))];
            }
            __builtin_amdgcn_s_setprio(1);
#pragma unroll
            for (int i = 0; i < 4; ++i)
#pragma unroll
                for (int j = 0; j < 4; ++j)
                    acc[i][j] = __builtin_amdgcn_mfma_f32_16x16x32_bf16(
                        af[i], bfr[j], acc[i][j], 0, 0, 0);
            __builtin_amdgcn_s_setprio(0);
        }
        asm volatile("" ::: "memory");         // fence: ds_reads stay above
        __builtin_amdgcn_s_barrier();          // tile t's buffer reusable
        cur = (cur == 2) ? 0 : cur + 1;
    }

    // epilogue: C/D layout col=lane&15, row=quad*4+reg (m89/m91)
#pragma unroll
    for (int i = 0; i < 4; ++i) {
#pragma unroll
        for (int j = 0; j < 4; ++j) {
            const int col = tileN + wn * 64 + j * 16 + r16;
#pragma unroll
            for (int r = 0; r < 4; ++r) {
                const int row = tileM + wm * 64 + i * 16 + q * 4 + r;
                C[(size_t)row * N + col] = acc[i][j][r];
            }
        }
    }
}

// ---------------------------------------------------------------------------
extern "C" void kernel_launch(void* const* d_in, const int* in_sizes, int n_in,
                              void* d_out, int out_size, void* d_ws, size_t ws_size,
                              hipStream_t stream) {
    const float* x  = (const float*)d_in[0];  // [4,4096,1280] fp32
    const float* W  = (const float*)d_in[1];  // [1280,1280]  fp32
    const float* K1 = (const float*)d_in[2];  // [4,4]
    const float* K2 = (const float*)d_in[3];  // [8,8]
    const float* K3 = (const float*)d_in[4];  // [40,40]
    float* out = (float*)d_out;               // [4,4096,1280] fp32

    const int D = 1280;
    const int M = in_sizes[0] / D;            // 16384
    const int N = D, K = D;

    // ws layout: [0, M*K) bf16 x ; then [+, N*K) bf16 Wrot
    __hip_bfloat16* x_bf = (__hip_bfloat16*)d_ws;
    __hip_bfloat16* Wrot = x_bf + (size_t)M * K;

    const int nConv = (M * K) / (256 * 8);    // 10240
    prep<<<nConv + D, 256, 0, stream>>>(x, W, K1, K2, K3, x_bf, Wrot, nConv);
    gemm_bt<<<(M / BM) * (N / BN), 512, 0, stream>>>(x_bf, Wrot, out, M, N, K);
}

// Round 2
// 219.106 us; speedup vs baseline: 1.1537x; 1.1537x over previous
//
#include <hip/hip_runtime.h>
#include <hip/hip_bf16.h>
#include <stdint.h>

typedef __bf16 bf16x8 __attribute__((ext_vector_type(8)));
typedef float floatx4 __attribute__((ext_vector_type(4)));

// ---------------------------------------------------------------------------
// Async global->LDS 16B copy (wave-uniform LDS base + lane*16; per-lane
// global address OK).
// ---------------------------------------------------------------------------
__device__ __forceinline__ void async_copy16(void* lds, const void* g) {
    __builtin_amdgcn_global_load_lds(
        (const __attribute__((address_space(1))) unsigned int*)g,
        (__attribute__((address_space(3))) unsigned int*)lds,
        16, 0, 0);
}

// ---------------------------------------------------------------------------
// Fused prep, one dispatch (UNCHANGED — isolate the gemm change):
//   blocks [0, nConv)         : x fp32 -> bf16 (8 elems/thread, float4 loads)
//   blocks [nConv, nConv+1280): Wrot[o,d] = sum_k kron(K1,K2,K3)[d,k] W[o,k]
// ---------------------------------------------------------------------------
__global__ __launch_bounds__(256)
void prep(const float* __restrict__ x,
          const float* __restrict__ W,
          const float* __restrict__ K1,
          const float* __restrict__ K2,
          const float* __restrict__ K3,
          __hip_bfloat16* __restrict__ x_bf,
          __hip_bfloat16* __restrict__ Wrot,
          int nConv) {
    const int tid = threadIdx.x;

    if ((int)blockIdx.x < nConv) {
        const size_t i = ((size_t)blockIdx.x * 256 + tid) * 8;
        const float4 a = *(const float4*)(x + i);
        const float4 b = *(const float4*)(x + i + 4);
        bf16x8 v;
        v[0] = (__bf16)a.x; v[1] = (__bf16)a.y; v[2] = (__bf16)a.z; v[3] = (__bf16)a.w;
        v[4] = (__bf16)b.x; v[5] = (__bf16)b.y; v[6] = (__bf16)b.z; v[7] = (__bf16)b.w;
        *(bf16x8*)((__bf16*)x_bf + i) = v;
        return;
    }

    const int o = blockIdx.x - nConv;
    __shared__ __align__(16) float w0[1280];   // W row, then stage-2 result
    __shared__ __align__(16) float t1[1280];
    __shared__ __align__(16) float k3s[1600];
    __shared__ float k2s[64];
    __shared__ float k1s[16];

    for (int i = tid; i < 1280; i += 256) w0[i] = W[o * 1280 + i];
    for (int i = tid; i < 1600; i += 256) k3s[i] = K3[i];
    if (tid < 64) k2s[tid] = K2[tid];
    if (tid < 16) k1s[tid] = K1[tid];
    __syncthreads();

    for (int i = tid; i < 1280; i += 256) {
        const int p = i / 40, d3 = i % 40;
        const float4* w4 = (const float4*)(w0 + p * 40);
        const float4* k4 = (const float4*)(k3s + d3 * 40);
        float acc = 0.f;
#pragma unroll
        for (int t = 0; t < 10; ++t) {
            const float4 a = w4[t], b = k4[t];
            acc += a.x * b.x + a.y * b.y + a.z * b.z + a.w * b.w;
        }
        t1[i] = acc;
    }
    __syncthreads();

    for (int i = tid; i < 1280; i += 256) {
        const int d3 = i % 40, pd = i / 40;
        const int k1 = pd >> 3, d2 = pd & 7;
        float acc = 0.f;
#pragma unroll
        for (int k2 = 0; k2 < 8; ++k2) acc += t1[(k1 * 8 + k2) * 40 + d3] * k2s[d2 * 8 + k2];
        w0[i] = acc;
    }
    __syncthreads();

    for (int i = tid; i < 1280; i += 256) {
        const int d3 = i % 40, pd = i / 40;
        const int d1 = pd >> 3, d2 = pd & 7;
        float acc = 0.f;
#pragma unroll
        for (int k1 = 0; k1 < 4; ++k1) acc += w0[(k1 * 8 + d2) * 40 + d3] * k1s[d1 * 4 + k1];
        Wrot[(size_t)o * 1280 + i] = __float2bfloat16(acc);
    }
}

// ---------------------------------------------------------------------------
// Main GEMM r8: C[m,n] = sum_k A[m,k] * B[n,k]   (bf16 in, fp32 out/acc)
//
// m201-style fine-grained phase schedule at shape-tuned geometry:
//   - BM=256, BN=320, BK=64; grid = 64*4 = 256 blocks EXACTLY = 1 block/CU,
//     one clean dispatch round, zero tail (vs 320 blk @62.5% or 640 @83%).
//   - 512 threads = 8 waves (2M x 4N), wave tile 128x80: acc[8][5] floatx4,
//     40 MFMA positions x 2 k-slices = 80 MFMA/K-tile/wave.
//   - dbuf LDS 144 KiB (A 2x32K, B 2x40K). XOR k-granule swizzle folded into
//     GLOBAL addresses (rule #21 both-sides; 0 conflicts measured r4).
//   - 4 phases per K-tile, each: {ds_read frags || stage 2-3 global_load_lds
//     || counted vmcnt || barrier || lgkmcnt(0)+sched_barrier || setprio(1)
//     20xMFMA setprio(0) || barrier}.  (m196: the fine interleave IS the
//     lever; coarse split was r7's regression.)
//   - vmcnt ledger (chunk stage order per iter: ph0[A0,A2,B0] ph1[B1,B2]
//     ph2[B3,B4] ph3[A1,A3]; phase reads: ph0/ph1 need A0,A2+all-B of tile t,
//     ph2/ph3 need A1,A3):
//       entering iter t (steady): outstanding = [A1,A3](t)           (2)
//       ph0: +3 -> 5                      (no wait)
//       ph1: +2 -> 7, vmcnt(5)  retires A1,A3(t)   -> ph2/ph3 reads safe
//       ph2: +2 -> 7                      (no wait)
//       ph3: +2 -> 9, vmcnt(2)  retires first-7 of t+1 -> next ph0/ph1 safe
//     Tail (t==nk-1): no stages; ph1 vmcnt(0); ph3 no wait.
//     Per-wave load counts uniform (A:4, B:5 chunks of 512 granules) --
//     required for per-wave vmcnt semantics.
//   - Numerics: per-acc accumulation order identical to r6 (t asc, s 0,1).
// ---------------------------------------------------------------------------
#define BM 256
#define BN 320
#define BK 64
#define AGRAN 2048   // BM*8 granules (16B each) per buffer = 32 KiB
#define BGRAN 2560   // BN*8 granules per buffer = 40 KiB

__global__ __launch_bounds__(512, 2)
void gemm_bt(const __hip_bfloat16* __restrict__ A,   // [M,K] bf16
             const __hip_bfloat16* __restrict__ B,   // [N,K] bf16
             float* __restrict__ C,                  // [M,N] fp32
             int M, int N, int K) {
    __shared__ bf16x8 As[2][AGRAN];   // 64 KiB
    __shared__ bf16x8 Bs[2][BGRAN];   // 80 KiB

    const int tid  = threadIdx.x;
    const int wave = tid >> 6;
    const int lane = tid & 63;
    const int q    = lane >> 4;
    const int r16  = lane & 15;
    const int wm   = wave >> 2;       // 0..1
    const int wn   = wave & 3;        // 0..3

    // XCD-partitioned tile assignment (grid = 64*4 = 256, 8 | 256)
    const int nTilesN = N / BN;               // 4
    const int chunkM  = (M / BM) >> 3;        // 8 M-tiles per XCD
    const int xcd = blockIdx.x & 7;
    const int s   = blockIdx.x >> 3;          // 0..31 within XCD
    const int bm  = xcd * chunkM + s / nTilesN;
    const int bn  = s % nTilesN;
    const int tileM = bm * BM, tileN = bn * BN;

    // Per-chunk global byte offsets (u32; A max ~42MB, B max ~3.3MB).
    // chunk c covers granules [c*512, c*512+512): row m = g>>3, phys slot
    // p = g&7 holds data k-granule kv = p ^ (m&7)  (XOR swizzle at source).
    uint32_t aoff[4], boff[5];
#pragma unroll
    for (int c = 0; c < 4; ++c) {
        const int g = c * 512 + tid;
        const int m = g >> 3, kv = (g & 7) ^ (m & 7);
        aoff[c] = (uint32_t)(((tileM + m) * K + kv * 8) * 2);
    }
#pragma unroll
    for (int c = 0; c < 5; ++c) {
        const int g = c * 512 + tid;
        const int m = g >> 3, kv = (g & 7) ^ (m & 7);
        boff[c] = (uint32_t)(((tileN + m) * K + kv * 8) * 2);
    }
    const char* Abase = (const char*)A;
    const char* Bbase = (const char*)B;

    // LDS fragment granule indices for k-slice 0; k-slice 1 = idx ^ 4
    // (kv=4|q and q<4 => (4|q)^x == (q^x)^4 for any x in 0..7).
    int ai[8], bi[5];
#pragma unroll
    for (int i = 0; i < 8; ++i) {
        const int m = wm * 128 + i * 16 + r16;
        ai[i] = m * 8 + (q ^ (m & 7));
    }
#pragma unroll
    for (int j = 0; j < 5; ++j) {
        const int n = wn * 80 + j * 16 + r16;
        bi[j] = n * 8 + (q ^ (n & 7));
    }

    floatx4 acc[8][5];
#pragma unroll
    for (int i = 0; i < 8; ++i)
#pragma unroll
        for (int j = 0; j < 5; ++j) acc[i][j] = (floatx4){0.f, 0.f, 0.f, 0.f};

    const int nk = K / BK;                    // 20

    // Prologue: stage tile 0 (9 loads/thread), full drain once, barrier.
#pragma unroll
    for (int c = 0; c < 4; ++c)
        async_copy16(&As[0][c * 512 + wave * 64], Abase + aoff[c]);
#pragma unroll
    for (int c = 0; c < 5; ++c)
        async_copy16(&Bs[0][c * 512 + wave * 64], Bbase + boff[c]);
    asm volatile("s_waitcnt vmcnt(0)" ::: "memory");
    __builtin_amdgcn_s_barrier();

    bf16x8 bf0[5], bf1[5], af[4];

    for (int t = 0; t < nk; ++t) {
        const int cur = t & 1, nxt = cur ^ 1;
        const uint32_t kb = (uint32_t)((t + 1) * BK * 2);
        const bool hn = (t + 1 < nk);

        // ---------------- phase 0: k-slice 0, rows i=0..3 ----------------
#pragma unroll
        for (int i = 0; i < 4; ++i) af[i] = As[cur][ai[i]];
#pragma unroll
        for (int j = 0; j < 5; ++j) bf0[j] = Bs[cur][bi[j]];
        if (hn) {
            async_copy16(&As[nxt][0 * 512 + wave * 64], Abase + aoff[0] + kb);
            async_copy16(&As[nxt][2 * 512 + wave * 64], Abase + aoff[2] + kb);
            async_copy16(&Bs[nxt][0 * 512 + wave * 64], Bbase + boff[0] + kb);
        }
        __builtin_amdgcn_sched_barrier(0);
        __builtin_amdgcn_s_barrier();
        asm volatile("s_waitcnt lgkmcnt(0)" ::: "memory");
        __builtin_amdgcn_sched_barrier(0);
        __builtin_amdgcn_s_setprio(1);
#pragma unroll
        for (int i = 0; i < 4; ++i)
#pragma unroll
            for (int j = 0; j < 5; ++j)
                acc[i][j] = __builtin_amdgcn_mfma_f32_16x16x32_bf16(
                    af[i], bf0[j], acc[i][j], 0, 0, 0);
        __builtin_amdgcn_s_setprio(0);
        __builtin_amdgcn_sched_barrier(0);
        __builtin_amdgcn_s_barrier();

        // ---------------- phase 1: k-slice 1, rows i=0..3 ----------------
#pragma unroll
        for (int i = 0; i < 4; ++i) af[i] = As[cur][ai[i] ^ 4];
#pragma unroll
        for (int j = 0; j < 5; ++j) bf1[j] = Bs[cur][bi[j] ^ 4];
        if (hn) {
            async_copy16(&Bs[nxt][1 * 512 + wave * 64], Bbase + boff[1] + kb);
            async_copy16(&Bs[nxt][2 * 512 + wave * 64], Bbase + boff[2] + kb);
            asm volatile("s_waitcnt vmcnt(5)" ::: "memory");   // retire A1,A3(t)
        } else {
            asm volatile("s_waitcnt vmcnt(0)" ::: "memory");   // tail drain
        }
        __builtin_amdgcn_sched_barrier(0);
        __builtin_amdgcn_s_barrier();
        asm volatile("s_waitcnt lgkmcnt(0)" ::: "memory");
        __builtin_amdgcn_sched_barrier(0);
        __builtin_amdgcn_s_setprio(1);
#pragma unroll
        for (int i = 0; i < 4; ++i)
#pragma unroll
            for (int j = 0; j < 5; ++j)
                acc[i][j] = __builtin_amdgcn_mfma_f32_16x16x32_bf16(
                    af[i], bf1[j], acc[i][j], 0, 0, 0);
        __builtin_amdgcn_s_setprio(0);
        __builtin_amdgcn_sched_barrier(0);
        __builtin_amdgcn_s_barrier();

        // ---------------- phase 2: k-slice 0, rows i=4..7 ----------------
#pragma unroll
        for (int i = 0; i < 4; ++i) af[i] = As[cur][ai[4 + i]];
        if (hn) {
            async_copy16(&Bs[nxt][3 * 512 + wave * 64], Bbase + boff[3] + kb);
            async_copy16(&Bs[nxt][4 * 512 + wave * 64], Bbase + boff[4] + kb);
        }
        __builtin_amdgcn_sched_barrier(0);
        __builtin_amdgcn_s_barrier();
        asm volatile("s_waitcnt lgkmcnt(0)" ::: "memory");
        __builtin_amdgcn_sched_barrier(0);
        __builtin_amdgcn_s_setprio(1);
#pragma unroll
        for (int i = 0; i < 4; ++i)
#pragma unroll
            for (int j = 0; j < 5; ++j)
                acc[4 + i][j] = __builtin_amdgcn_mfma_f32_16x16x32_bf16(
                    af[i], bf0[j], acc[4 + i][j], 0, 0, 0);
        __builtin_amdgcn_s_setprio(0);
        __builtin_amdgcn_sched_barrier(0);
        __builtin_amdgcn_s_barrier();

        // ---------------- phase 3: k-slice 1, rows i=4..7 ----------------
#pragma unroll
        for (int i = 0; i < 4; ++i) af[i] = As[cur][ai[4 + i] ^ 4];
        if (hn) {
            async_copy16(&As[nxt][1 * 512 + wave * 64], Abase + aoff[1] + kb);
            async_copy16(&As[nxt][3 * 512 + wave * 64], Abase + aoff[3] + kb);
            asm volatile("s_waitcnt vmcnt(2)" ::: "memory");   // first-7 of t+1 land
        }
        __builtin_amdgcn_sched_barrier(0);
        __builtin_amdgcn_s_barrier();
        asm volatile("s_waitcnt lgkmcnt(0)" ::: "memory");
        __builtin_amdgcn_sched_barrier(0);
        __builtin_amdgcn_s_setprio(1);
#pragma unroll
        for (int i = 0; i < 4; ++i)
#pragma unroll
            for (int j = 0; j < 5; ++j)
                acc[4 + i][j] = __builtin_amdgcn_mfma_f32_16x16x32_bf16(
                    af[i], bf1[j], acc[4 + i][j], 0, 0, 0);
        __builtin_amdgcn_s_setprio(0);
        __builtin_amdgcn_sched_barrier(0);
        __builtin_amdgcn_s_barrier();
    }

    // epilogue: C/D layout col=lane&15, row=quad*4+reg (m89/m91)
#pragma unroll
    for (int i = 0; i < 8; ++i) {
#pragma unroll
        for (int j = 0; j < 5; ++j) {
            const int col = tileN + wn * 80 + j * 16 + r16;
#pragma unroll
            for (int r = 0; r < 4; ++r) {
                const int row = tileM + wm * 128 + i * 16 + q * 4 + r;
                C[(size_t)row * N + col] = acc[i][j][r];
            }
        }
    }
}

// ---------------------------------------------------------------------------
extern "C" void kernel_launch(void* const* d_in, const int* in_sizes, int n_in,
                              void* d_out, int out_size, void* d_ws, size_t ws_size,
                              hipStream_t stream) {
    const float* x  = (const float*)d_in[0];  // [4,4096,1280] fp32
    const float* W  = (const float*)d_in[1];  // [1280,1280]  fp32
    const float* K1 = (const float*)d_in[2];  // [4,4]
    const float* K2 = (const float*)d_in[3];  // [8,8]
    const float* K3 = (const float*)d_in[4];  // [40,40]
    float* out = (float*)d_out;               // [4,4096,1280] fp32

    const int D = 1280;
    const int M = in_sizes[0] / D;            // 16384
    const int N = D, K = D;

    // ws layout: [0, M*K) bf16 x ; then [+, N*K) bf16 Wrot
    __hip_bfloat16* x_bf = (__hip_bfloat16*)d_ws;
    __hip_bfloat16* Wrot = x_bf + (size_t)M * K;

    const int nConv = (M * K) / (256 * 8);    // 10240
    prep<<<nConv + D, 256, 0, stream>>>(x, W, K1, K2, K3, x_bf, Wrot, nConv);
    gemm_bt<<<(M / BM) * (N / BN), 512, 0, stream>>>(x_bf, Wrot, out, M, N, K);
}